// Round 4
// baseline (67.344 us; speedup 1.0000x reference)
//
#include <hip/hip_runtime.h>
#include <math.h>

#define BB 4
#define TT 1024
#define HH 16
#define NROWS 64   // 2*BINS table rows
#define RPAD 20    // padded row floats (80 B: 16B-aligned, row-start bank period 8)

#define PI_F    3.14159265358979323846f
#define TWOPI_F 6.28318530717958647692f

typedef float f4 __attribute__((ext_vector_type(4)));

// ---------------- Kernel A: global eta range (1 block) ----------------
__global__ void QuantizedRPE_range_kernel(const float* __restrict__ coords,
                                          float* __restrict__ ws) {
    int lane = threadIdx.x & 63;
    int b = threadIdx.x >> 6;  // 4 waves, one batch each
    float mx = -1e30f, mn = 1e30f;
    #pragma unroll
    for (int it = 0; it < TT / 64; ++it) {
        float e = coords[(size_t)(b * TT + lane + it * 64) * 2];
        mx = fmaxf(mx, e);
        mn = fminf(mn, e);
    }
    #pragma unroll
    for (int m = 32; m; m >>= 1) {
        mx = fmaxf(mx, __shfl_xor(mx, m));
        mn = fminf(mn, __shfl_xor(mn, m));
    }
    __shared__ float sr[BB];
    if (lane == 0) sr[b] = mx - mn;
    __syncthreads();
    if (threadIdx.x == 0) {
        float r = fmaxf(fmaxf(sr[0], sr[1]), fmaxf(sr[2], sr[3]));
        ws[0] = fmaxf(r, 1e-6f);
    }
}

// ---------------- Kernel B: bias fill ----------------
// One block per (b,i). Thread t owns j = 4t..4t+3; per j, read each needed
// table row as 4x ds_read_b128 from row-major LDS, add, transpose in regs,
// nontemporal float4 store per h-plane (write-once data: bypass L2 allocate).
__global__ __launch_bounds__(256) void QuantizedRPE_fill_kernel(
        const float* __restrict__ coords,
        const float* __restrict__ table,
        const float* __restrict__ ws,
        float* __restrict__ out) {
    __shared__ float tl[NROWS][RPAD];   // [row][h]; rows 0..31 eta, 32..63 phi
    int tid = threadIdx.x;

    // stage table: 256 x float4 covers 64 rows x 16 floats exactly
    {
        f4 t4 = ((const f4*)table)[tid];
        int row = tid >> 2, col = (tid & 3) * 4;
        *(f4*)&tl[row][col] = t4;
    }

    float range = ws[0];
    int b = blockIdx.x >> 10;
    int i = blockIdx.x & (TT - 1);
    float ei  = coords[(size_t)(b * TT + i) * 2 + 0];
    float pii = coords[(size_t)(b * TT + i) * 2 + 1];
    __syncthreads();

    int j0 = tid * 4;
    const f4* cp = (const f4*)(coords + (size_t)(b * TT + j0) * 2);
    f4 c01 = cp[0];
    f4 c23 = cp[1];
    float ej[4] = {c01.x, c01.z, c23.x, c23.z};
    float pj[4] = {c01.y, c01.w, c23.y, c23.w};

    float s[4][16];   // s[j][h], all indices compile-time after unroll
    #pragma unroll
    for (int jj = 0; jj < 4; ++jj) {
        // eta bin: same op order as reference (bit-exact, frozen)
        float re = ei - ej[jj];
        int be = (int)(re / range * 16.0f);
        be = min(max(be, -16), 15);
        int eidx = be + 16;                 // [0,32)
        // phi wrap: fmod + sign-fix == np.mod (exact)
        float w = (pii - pj[jj]) + PI_F;
        float m = fmodf(w, TWOPI_F);
        if (m < 0.0f) m += TWOPI_F;
        float rp = m - PI_F;
        int bp = (int)(rp / PI_F * 16.0f);
        bp = min(max(bp, -16), 15);
        int pidx = bp + 48;                 // [32,64)

        const f4* er = (const f4*)&tl[eidx][0];   // 4x ds_read_b128
        const f4* pr = (const f4*)&tl[pidx][0];
        #pragma unroll
        for (int q = 0; q < 4; ++q) {
            f4 a = er[q];
            f4 c = pr[q];
            s[jj][q * 4 + 0] = a.x + c.x;
            s[jj][q * 4 + 1] = a.y + c.y;
            s[jj][q * 4 + 2] = a.z + c.z;
            s[jj][q * 4 + 3] = a.w + c.w;
        }
    }

    float* op = out + ((size_t)(b * HH) * TT + i) * TT + j0;
    #pragma unroll
    for (int h = 0; h < HH; ++h) {
        f4 v = {s[0][h], s[1][h], s[2][h], s[3][h]};
        __builtin_nontemporal_store(v, (f4*)(op + (size_t)h * TT * TT));
    }
}

extern "C" void kernel_launch(void* const* d_in, const int* in_sizes, int n_in,
                              void* d_out, int out_size, void* d_ws, size_t ws_size,
                              hipStream_t stream) {
    const float* coords = (const float*)d_in[0];   // [4,1024,2] f32
    const float* table  = (const float*)d_in[1];   // [64,16]   f32
    float* out = (float*)d_out;                    // [4,16,1024,1024] f32
    float* ws  = (float*)d_ws;

    QuantizedRPE_range_kernel<<<1, 256, 0, stream>>>(coords, ws);
    QuantizedRPE_fill_kernel<<<BB * TT, 256, 0, stream>>>(coords, table, ws, out);
}

// Round 5
// 46.420 us; speedup vs baseline: 1.4507x; 1.4507x over previous
//
#include <hip/hip_runtime.h>
#include <math.h>

#define BB 4
#define TT 1024
#define HH 16
#define NROWS 64   // 2*BINS table rows
#define RPAD 20    // padded row floats (80 B: 16B-aligned, row-start bank period 8)
#define ROWS_PER_BLOCK 4

#define PI_F    3.14159265358979323846f
#define TWOPI_F 6.28318530717958647692f

typedef float f4 __attribute__((ext_vector_type(4)));

// Fused kernel: per-block redundant eta-range reduce (L2-resident, amortized
// over 4 rows) + table stage + 4 output rows per block.
// Grid: 1024 blocks; block q: b = q>>8, i0 = (q&255)*4.
__global__ __launch_bounds__(256) void QuantizedRPE_fused_kernel(
        const float* __restrict__ coords,
        const float* __restrict__ table,
        float* __restrict__ out) {
    __shared__ float tl[NROWS][RPAD];   // [row][h]; rows 0..31 eta, 32..63 phi
    __shared__ float sre[BB];
    int tid = threadIdx.x;
    int lane = tid & 63;
    int w = tid >> 6;

    // ---- stage table: 256 x float4 covers 64 rows x 16 floats ----
    {
        f4 t4 = ((const f4*)table)[tid];
        int row = tid >> 2, col = (tid & 3) * 4;
        *(f4*)&tl[row][col] = t4;
    }

    // ---- global eta range: wave w reduces batch w (f4 = 2 coord pairs) ----
    {
        const f4* cp4 = (const f4*)coords;   // f4 k: {eta(2k),phi(2k),eta(2k+1),phi(2k+1)} within batch
        float mx = -1e30f, mn = 1e30f;
        #pragma unroll
        for (int it = 0; it < TT / 128; ++it) {     // 512 f4 per batch / 64 lanes
            f4 v = cp4[(size_t)w * (TT / 2) + lane + it * 64];
            mx = fmaxf(mx, fmaxf(v.x, v.z));
            mn = fminf(mn, fminf(v.x, v.z));
        }
        #pragma unroll
        for (int m = 32; m; m >>= 1) {
            mx = fmaxf(mx, __shfl_xor(mx, m));
            mn = fminf(mn, __shfl_xor(mn, m));
        }
        if (lane == 0) sre[w] = mx - mn;
    }
    __syncthreads();
    float range = fmaxf(fmaxf(fmaxf(sre[0], sre[1]), fmaxf(sre[2], sre[3])), 1e-6f);

    int b  = blockIdx.x >> 8;
    int i0 = (blockIdx.x & 255) * ROWS_PER_BLOCK;

    // j-coords: row-invariant, load once per block
    int j0 = tid * 4;
    const f4* cp = (const f4*)(coords + (size_t)(b * TT + j0) * 2);
    f4 c01 = cp[0];
    f4 c23 = cp[1];
    float ej[4] = {c01.x, c01.z, c23.x, c23.z};
    float pj[4] = {c01.y, c01.w, c23.y, c23.w};

    #pragma unroll
    for (int r = 0; r < ROWS_PER_BLOCK; ++r) {
        int i = i0 + r;
        float ei  = coords[(size_t)(b * TT + i) * 2 + 0];
        float pii = coords[(size_t)(b * TT + i) * 2 + 1];

        float s[4][16];   // s[j][h], all indices compile-time after unroll
        #pragma unroll
        for (int jj = 0; jj < 4; ++jj) {
            // eta bin: same op order as reference (bit-exact, frozen)
            float re = ei - ej[jj];
            int be = (int)(re / range * 16.0f);
            be = min(max(be, -16), 15);
            int eidx = be + 16;                 // [0,32)
            // phi wrap: fmod + sign-fix == np.mod (exact)
            float ww = (pii - pj[jj]) + PI_F;
            float m = fmodf(ww, TWOPI_F);
            if (m < 0.0f) m += TWOPI_F;
            float rp = m - PI_F;
            int bp = (int)(rp / PI_F * 16.0f);
            bp = min(max(bp, -16), 15);
            int pidx = bp + 48;                 // [32,64)

            const f4* er = (const f4*)&tl[eidx][0];   // 4x ds_read_b128
            const f4* pr = (const f4*)&tl[pidx][0];
            #pragma unroll
            for (int q = 0; q < 4; ++q) {
                f4 a = er[q];
                f4 c = pr[q];
                s[jj][q * 4 + 0] = a.x + c.x;
                s[jj][q * 4 + 1] = a.y + c.y;
                s[jj][q * 4 + 2] = a.z + c.z;
                s[jj][q * 4 + 3] = a.w + c.w;
            }
        }

        float* op = out + ((size_t)(b * HH) * TT + i) * TT + j0;
        #pragma unroll
        for (int h = 0; h < HH; ++h) {
            f4 v = {s[0][h], s[1][h], s[2][h], s[3][h]};
            *(f4*)(op + (size_t)h * TT * TT) = v;
        }
    }
}

extern "C" void kernel_launch(void* const* d_in, const int* in_sizes, int n_in,
                              void* d_out, int out_size, void* d_ws, size_t ws_size,
                              hipStream_t stream) {
    const float* coords = (const float*)d_in[0];   // [4,1024,2] f32
    const float* table  = (const float*)d_in[1];   // [64,16]   f32
    float* out = (float*)d_out;                    // [4,16,1024,1024] f32
    (void)d_ws; (void)ws_size;

    QuantizedRPE_fused_kernel<<<BB * TT / ROWS_PER_BLOCK, 256, 0, stream>>>(coords, table, out);
}